// Round 11
// baseline (845.230 us; speedup 1.0000x reference)
//
#include <hip/hip_runtime.h>

// Dilated conv2d, round 11: LDS-free implicit GEMM.
// K1: transpose x [b][cin][h][w] f32 -> padded xT [b][h'][w'][cin] bf16 in d_ws
//     (h'=ih+2 in [0,516), w'=iw+4 in [0,536), zero borders; f2bf folded in).
// K2: conv with BOTH operands streamed from global/L1/L2:
//     B-frag = 1KB fully-coalesced load from xT (li*64B + h*16B contiguous);
//     A-frag from repacked weights (as r9). No LDS, no barriers, no staging.
//     Block = (wt, oh-pair same parity, b), 4 waves (wo x wp), independent.
//     12 waves/CU (launch_bounds 256,3) vs r9's LDS-pinned 8.
// Fallback: if ws_size < 141.8 MB, run the proven round-9 ring kernel.

#define CIN 32
#define HH 512
#define WW 512
#define COUT 64
#define OH 508
#define OW 496
#define KH 5
#define KW 9

#define XT_H 516            // rows ih = -2..513  (h' = ih+2)
#define XT_W 536            // cols iw = -4..531  (w' = iw+4)
#define XT_ROW (XT_W * CIN)         // 17152 elts per row
#define XT_BATCH ((size_t)XT_H * XT_ROW)  // 8,850,432 elts per batch
#define XT_ELTS ((size_t)8 * XT_BATCH)    // 70,803,456
#define XT_BYTES (XT_ELTS * 2)            // 141,606,912
#define WREP_BYTES (KH * KW * COUT * CIN * 2)  // 184,320

typedef short short8 __attribute__((ext_vector_type(8)));
typedef float floatx4 __attribute__((ext_vector_type(4)));
typedef unsigned short u16;
typedef unsigned int u32;

__device__ __forceinline__ u16 f2bf(float f) {  // RNE f32->bf16
    u32 u = __float_as_uint(f);
    return (u16)((u + 0x7fffu + ((u >> 16) & 1u)) >> 16);
}

__global__ void repack_w_k(const float* __restrict__ w, u16* __restrict__ wr) {
    int idx = blockIdx.x * 256 + threadIdx.x;
    if (idx >= KH * KW * COUT * CIN) return;
    int tap = idx / (COUT * CIN);
    int rem = idx - tap * (COUT * CIN);
    int co = rem / CIN;
    int ci = rem - co * CIN;
    int r  = tap / KW;
    int kw = tap - r * KW;
    wr[idx] = f2bf(w[((co * CIN + ci) * KH + r) * KW + kw]);
}

// ---------------- K1: transpose + convert + pad ----------------
__global__ __launch_bounds__(256)
void transpose_x(const float* __restrict__ x, u16* __restrict__ xT) {
    int wq = blockIdx.x * 256 + threadIdx.x;   // w' 0..535
    int hp = blockIdx.y;                       // h' 0..515
    int b  = blockIdx.z;
    if (wq >= XT_W) return;
    int ih = hp - 2, iw = wq - 4;
    bool ok = ((unsigned)ih < HH) && ((unsigned)iw < WW);
    const float* xp = x + ((size_t)b * CIN) * (HH * WW) + (size_t)ih * WW + iw;
    u16 v[32];
    #pragma unroll
    for (int c = 0; c < 32; ++c)
        v[c] = ok ? f2bf(xp[(size_t)c * (HH * WW)]) : (u16)0;
    u16* dst = xT + (((size_t)b * XT_H + hp) * XT_W + wq) * CIN;
    #pragma unroll
    for (int k = 0; k < 4; ++k)
        *(uint4*)(dst + 8 * k) = *(const uint4*)&v[8 * k];
}

// ---------------- K2: LDS-free conv ----------------
__global__ __launch_bounds__(256, 3)
void conv_gl(const u16* __restrict__ xT, const u16* __restrict__ wrep,
             float* __restrict__ out) {
    const int wt = blockIdx.x;                 // 0..3
    const int gy = blockIdx.y;                 // 0..253
    const int b  = blockIdx.z;                 // 0..7
    const int p   = gy & 1;
    const int idx = gy >> 1;                   // 0..126
    const int w0  = wt * 128;

    const int tid  = threadIdx.x;
    const int lane = tid & 63;
    const int wave = tid >> 6;
    const int wp   = wave & 1;                 // pos half (64)
    const int wo   = wave >> 1;                // which oh of the pair
    const int li   = lane & 15;
    const int h    = lane >> 4;                // 0..3

    const int oh = p + 4 * idx + 2 * wo;       // <= 507

    // A: lane -> co=li (within 16), cin = 8h..8h+7
    const u16* abase0 = wrep + li * CIN + 8 * h;
    // B: frag base = (row=oh+2r, col=w0+64wp+li, cin=8h); 64 lanes contiguous 1KB
    const u16* bbase = xT + (((size_t)b * XT_H + oh) * XT_W + (w0 + 64 * wp + li)) * CIN + 8 * h;

    floatx4 acc[4][4];
    #pragma unroll
    for (int mi = 0; mi < 4; ++mi)
        #pragma unroll
        for (int ni = 0; ni < 4; ++ni)
            acc[mi][ni] = (floatx4){0.f, 0.f, 0.f, 0.f};

    #pragma unroll 1
    for (int r = 0; r < KH; ++r) {
        const u16* bb = bbase + (size_t)r * (2 * XT_ROW);
        const u16* ab = abase0 + (size_t)(r * KW) * (COUT * CIN);
        #pragma unroll
        for (int kw = 0; kw < KW; ++kw) {
            short8 af[4], bf_[4];
            #pragma unroll
            for (int mi = 0; mi < 4; ++mi)
                af[mi] = *(const short8*)(ab + (kw * COUT + mi * 16) * CIN);
            #pragma unroll
            for (int ni = 0; ni < 4; ++ni)
                bf_[ni] = *(const short8*)(bb + (3 * kw + 16 * ni) * CIN);
            __builtin_amdgcn_s_setprio(1);
            #pragma unroll
            for (int mi = 0; mi < 4; ++mi)
                #pragma unroll
                for (int ni = 0; ni < 4; ++ni)
                    acc[mi][ni] = __builtin_amdgcn_mfma_f32_16x16x32_bf16(
                        af[mi], bf_[ni], acc[mi][ni], 0, 0, 0);
            __builtin_amdgcn_s_setprio(0);
        }
    }

    // store: col=li -> pos, co = 16*mi + 4*h + reg
    #pragma unroll
    for (int ni = 0; ni < 4; ++ni) {
        const int posb = w0 + 64 * wp + 16 * ni;
        if (posb < OW) {
            const int pos = posb + li;
            #pragma unroll
            for (int mi = 0; mi < 4; ++mi) {
                float* op = out + (((size_t)(b * COUT + 16 * mi + 4 * h) * OH + oh) * OW) + pos;
                #pragma unroll
                for (int reg = 0; reg < 4; ++reg)
                    op[(size_t)reg * OH * OW] = acc[mi][ni][reg];
            }
        }
    }
}

// ---------------- Fallback: round-9 parity-ring kernel ----------------
#define WTILE 128
#define SW 152
#define OCT_STRIDE 1224
#define SLOT_STRIDE 4896
#define NSLOT 8
#define NIT 304
#define STEPS 16

__global__ __launch_bounds__(256, 2)
void conv_ring(const float* __restrict__ x, const u16* __restrict__ wrep,
               float* __restrict__ out) {
    __shared__ u16 s[NSLOT * SLOT_STRIDE];

    const int bx     = blockIdx.x;
    const int wt     = bx & 3;
    const int parity = bx >> 2;
    const int chunk  = blockIdx.y;
    const int b      = blockIdx.z;
    const int w0     = wt * WTILE;
    const int oh0    = parity + 64 * chunk;
    const int ihbase = oh0 - 2;
    const int iwbase = w0 - 4;

    const int tid  = threadIdx.x;
    const int lane = tid & 63;
    const int wave = tid >> 6;
    const int wp   = wave & 1;
    const int wo   = wave >> 1;
    const int li   = lane & 15;
    const int h    = lane >> 4;

    const size_t cstr = (size_t)HH * WW;
    const float* xb = x + (size_t)b * CIN * cstr;

    for (int it = tid; it < 6 * NIT; it += 256) {
        int j   = it / NIT;
        int rem = it - j * NIT;
        int w4  = rem >> 3;
        int q   = rem & 7;
        int ih  = ihbase + 2 * j;
        int iw0 = iwbase + 4 * w4;
        float4 m0 = {0,0,0,0}, m1 = {0,0,0,0}, m2 = {0,0,0,0}, m3 = {0,0,0,0};
        if ((unsigned)ih < HH && (unsigned)iw0 < WW) {
            const float* pp = xb + (size_t)(4 * q) * cstr + (size_t)ih * WW + iw0;
            m0 = *(const float4*)(pp);
            m1 = *(const float4*)(pp + cstr);
            m2 = *(const float4*)(pp + 2 * cstr);
            m3 = *(const float4*)(pp + 3 * cstr);
        }
        u16* dst = s + (j & 7) * SLOT_STRIDE + (q >> 1) * OCT_STRIDE + (q & 1) * 4;
        const float* f0 = (const float*)&m0; const float* f1 = (const float*)&m1;
        const float* f2 = (const float*)&m2; const float* f3 = (const float*)&m3;
        #pragma unroll
        for (int jj = 0; jj < 4; ++jj) {
            u32 lo = (u32)f2bf(f0[jj]) | ((u32)f2bf(f1[jj]) << 16);
            u32 hi = (u32)f2bf(f2[jj]) | ((u32)f2bf(f3[jj]) << 16);
            *(uint2*)(dst + (4 * w4 + jj) * 8) = make_uint2(lo, hi);
        }
    }
    __syncthreads();

    const u16* abase0 = wrep + li * CIN + 8 * h;
    const int  bfixed = h * OCT_STRIDE + (64 * wp + li) * 8;

    floatx4 acc[4][4];

    #pragma unroll 1
    for (int st = 0; st < STEPS; ++st) {
        #pragma unroll
        for (int mi = 0; mi < 4; ++mi)
            #pragma unroll
            for (int ni = 0; ni < 4; ++ni)
                acc[mi][ni] = (floatx4){0.f, 0.f, 0.f, 0.f};

        const bool doPref = (st < STEPS - 1);
        float4 pv[3][4];
        #pragma unroll
        for (int k = 0; k < 3; ++k) {
            #pragma unroll
            for (int c = 0; c < 4; ++c) pv[k][c] = (float4){0,0,0,0};
            int it = tid + 256 * k;
            if (doPref && it < 2 * NIT) {
                int second = (it >= NIT);
                int rem = it - (second ? NIT : 0);
                int j   = 2 * st + 6 + second;
                int w4  = rem >> 3;
                int q   = rem & 7;
                int ih  = ihbase + 2 * j;
                int iw0 = iwbase + 4 * w4;
                if ((unsigned)ih < HH && (unsigned)iw0 < WW) {
                    const float* pp = xb + (size_t)(4 * q) * cstr + (size_t)ih * WW + iw0;
                    pv[k][0] = *(const float4*)(pp);
                    pv[k][1] = *(const float4*)(pp + cstr);
                    pv[k][2] = *(const float4*)(pp + 2 * cstr);
                    pv[k][3] = *(const float4*)(pp + 3 * cstr);
                }
            }
        }

        const int js = 2 * st;
        #pragma unroll 1
        for (int r = 0; r < KH; ++r) {
            const u16* bb = s + ((js + wo + r) & 7) * SLOT_STRIDE + bfixed;
            const u16* ab = abase0 + (size_t)(r * KW) * (COUT * CIN);
            #pragma unroll
            for (int kw = 0; kw < KW; ++kw) {
                short8 af[4], bf_[4];
                #pragma unroll
                for (int mi = 0; mi < 4; ++mi)
                    af[mi] = *(const short8*)(ab + (kw * COUT + mi * 16) * CIN);
                #pragma unroll
                for (int ni = 0; ni < 4; ++ni)
                    bf_[ni] = *(const short8*)(bb + (16 * ni + 3 * kw) * 8);
                __builtin_amdgcn_s_setprio(1);
                #pragma unroll
                for (int mi = 0; mi < 4; ++mi)
                    #pragma unroll
                    for (int ni = 0; ni < 4; ++ni)
                        acc[mi][ni] = __builtin_amdgcn_mfma_f32_16x16x32_bf16(
                            af[mi], bf_[ni], acc[mi][ni], 0, 0, 0);
                __builtin_amdgcn_s_setprio(0);
            }
        }

        if (doPref) {
            #pragma unroll
            for (int k = 0; k < 3; ++k) {
                int it = tid + 256 * k;
                if (it < 2 * NIT) {
                    int second = (it >= NIT);
                    int rem = it - (second ? NIT : 0);
                    int j   = 2 * st + 6 + second;
                    int w4  = rem >> 3;
                    int q   = rem & 7;
                    u16* dst = s + (j & 7) * SLOT_STRIDE + (q >> 1) * OCT_STRIDE + (q & 1) * 4;
                    const float* f0 = (const float*)&pv[k][0];
                    const float* f1 = (const float*)&pv[k][1];
                    const float* f2 = (const float*)&pv[k][2];
                    const float* f3 = (const float*)&pv[k][3];
                    #pragma unroll
                    for (int jj = 0; jj < 4; ++jj) {
                        u32 lo = (u32)f2bf(f0[jj]) | ((u32)f2bf(f1[jj]) << 16);
                        u32 hi = (u32)f2bf(f2[jj]) | ((u32)f2bf(f3[jj]) << 16);
                        *(uint2*)(dst + (4 * w4 + jj) * 8) = make_uint2(lo, hi);
                    }
                }
            }
        }
        __syncthreads();

        const int oh = oh0 + 4 * st + 2 * wo;
        if (oh < OH) {
            #pragma unroll
            for (int ni = 0; ni < 4; ++ni) {
                const int posb = w0 + 64 * wp + 16 * ni;
                if (posb < OW) {
                    const int pos = posb + li;
                    #pragma unroll
                    for (int mi = 0; mi < 4; ++mi) {
                        float* op = out + (((size_t)(b * COUT + 16 * mi + 4 * h) * OH + oh) * OW) + pos;
                        #pragma unroll
                        for (int reg = 0; reg < 4; ++reg)
                            op[(size_t)reg * OH * OW] = acc[mi][ni][reg];
                    }
                }
            }
        }
    }
}

extern "C" void kernel_launch(void* const* d_in, const int* in_sizes, int n_in,
                              void* d_out, int out_size, void* d_ws, size_t ws_size,
                              hipStream_t stream) {
    const float* x = (const float*)d_in[0];
    const float* w = (const float*)d_in[1];
    float* out = (float*)d_out;

    if (ws_size >= XT_BYTES + WREP_BYTES) {
        u16* xT   = (u16*)d_ws;
        u16* wrep = (u16*)((char*)d_ws + XT_BYTES);
        repack_w_k<<<(KH * KW * COUT * CIN + 255) / 256, 256, 0, stream>>>(w, wrep);
        dim3 tg((XT_W + 255) / 256, XT_H, 8);
        transpose_x<<<tg, 256, 0, stream>>>(x, xT);
        dim3 cg(4, 254, 8);
        conv_gl<<<cg, 256, 0, stream>>>(xT, wrep, out);
    } else {
        u16* wrep = (u16*)d_ws;
        repack_w_k<<<(KH * KW * COUT * CIN + 255) / 256, 256, 0, stream>>>(w, wrep);
        dim3 grid(8, 8, 8);
        conv_ring<<<grid, dim3(256), 0, stream>>>(x, wrep, out);
    }
}

// Round 12
// 486.160 us; speedup vs baseline: 1.7386x; 1.7386x over previous
//
#include <hip/hip_runtime.h>

// Dilated conv2d, round 12: all-LDS-operand implicit GEMM with DMA staging.
// Insight from r9/r11 budgets: every port is below the 430k-cyc/CU MFMA floor;
// the wall is LATENCY serialization (A from L1/L2 ~250cyc x small reg window).
// Fix: both MFMA operands from LDS; staging via global_load_lds (no VALU, no
// pv regs).  K1 pre-transposes x -> xT[b][h'][w'][cin] bf16 so ring slots are
// contiguous 10KB DMA copies.
// Block = whole CU: 512 thr / 8 waves, 1 block/CU (LDS 156KB), 256 blocks.
// Step = 4 same-parity oh rows; wave = 64co x 64pos (wo=wave&3 row, wp pos).
// LDS: 12-slot ring [wi=160][cin=32] bf16 (10KB/slot) + 36.9KB wbuf (per-r
// weights, re-DMA'd each r from L2-resident wrep).  A/B frags = contiguous
// 1KB ds_read_b128, conflict-free.  2 barriers per r-row; the 2nd drains the
// DMA (implicit vmcnt(0)).

#define CIN 32
#define HH 512
#define WW 512
#define COUT 64
#define OH 508
#define OW 496
#define KH 5
#define KW 9

#define XT_H 516
#define XT_W 544
#define XT_ROW (XT_W * CIN)                    // 17408 elts
#define XT_ELTS ((size_t)8 * XT_H * XT_ROW)    // 71,860,224
#define XT_BYTES (XT_ELTS * 2)                 // 143,720,448
#define WREP_BYTES (KH * KW * COUT * CIN * 2)  // 184,320

// main conv geometry
#define WT2 128                 // pos tile
#define SLOT_W 160              // slot width (reads use <=152)
#define SLOT_E (SLOT_W * CIN)   // 5120 elts = 10KB
#define NSL 12                  // ring slots (8 active + 4 prefetch)
#define RING_E (NSL * SLOT_E)   // 61440 elts
#define WBUF_E (KW * COUT * CIN) // 18432 elts = 36864B (one r-row of weights)
#define STEPS2 16               // 4 rows/step -> 64 parity-rows per block

typedef short short8 __attribute__((ext_vector_type(8)));
typedef float floatx4 __attribute__((ext_vector_type(4)));
typedef unsigned short u16;
typedef unsigned int u32;

__device__ __forceinline__ u16 f2bf(float f) {  // RNE f32->bf16
    u32 u = __float_as_uint(f);
    return (u16)((u + 0x7fffu + ((u >> 16) & 1u)) >> 16);
}

__device__ __forceinline__ void gl2lds(const u16* g, u16* l) {
    __builtin_amdgcn_global_load_lds(
        (const __attribute__((address_space(1))) unsigned int*)g,
        (__attribute__((address_space(3))) unsigned int*)l, 16, 0, 0);
}

__global__ void repack_w_k(const float* __restrict__ w, u16* __restrict__ wr) {
    int idx = blockIdx.x * 256 + threadIdx.x;
    if (idx >= KH * KW * COUT * CIN) return;
    int tap = idx / (COUT * CIN);
    int rem = idx - tap * (COUT * CIN);
    int co = rem / CIN;
    int ci = rem - co * CIN;
    int r  = tap / KW;
    int kw = tap - r * KW;
    wr[idx] = f2bf(w[((co * CIN + ci) * KH + r) * KW + kw]);
}

// K1: x [b][cin][h][w] f32 -> xT [b][h'=ih+2][w'=iw+4][cin] bf16, zero-padded.
__global__ __launch_bounds__(256)
void transpose_x(const float* __restrict__ x, u16* __restrict__ xT) {
    int wq = blockIdx.x * 256 + threadIdx.x;   // 0..543
    int hp = blockIdx.y;                       // 0..515
    int b  = blockIdx.z;
    if (wq >= XT_W) return;
    int ih = hp - 2, iw = wq - 4;
    bool ok = ((unsigned)ih < HH) && ((unsigned)iw < WW);
    const float* xp = x + ((size_t)b * CIN) * (HH * WW) + (size_t)ih * WW + iw;
    u16 v[32];
    #pragma unroll
    for (int c = 0; c < 32; ++c)
        v[c] = ok ? f2bf(xp[(size_t)c * (HH * WW)]) : (u16)0;
    u16* dst = xT + (((size_t)b * XT_H + hp) * XT_W + wq) * CIN;
    #pragma unroll
    for (int k = 0; k < 4; ++k)
        *(uint4*)(dst + 8 * k) = *(const uint4*)&v[8 * k];
}

// K2: the conv.
__global__ __launch_bounds__(512, 1)
void conv_lds(const u16* __restrict__ xT, const u16* __restrict__ wrep,
              float* __restrict__ out) {
    __shared__ u16 s[RING_E + WBUF_E];         // 159,744 B

    const int wt     = blockIdx.x & 3;
    const int parity = blockIdx.x >> 2;
    const int chunk  = blockIdx.y;             // 0..3 (64 parity-rows each)
    const int b      = blockIdx.z;
    const int w0     = wt * WT2;
    const int jbase  = 64 * chunk;

    const int tid  = threadIdx.x;
    const int lane = tid & 63;
    const int wave = tid >> 6;                 // 0..7
    const int wo   = wave & 3;                 // row within step
    const int wp   = wave >> 2;                // pos half (64)
    const int li   = lane & 15;
    const int h    = lane >> 4;

    u16* wb = &s[RING_E];

    // ---- DMA helpers (issue-only; drain via __syncthreads) ----
    // stage one x row (local parity-row jj) into slot jj%12: 10 x 1KB chunks.
    #define STAGE_X_ROW(jj_) do {                                             \
        int hp_ = parity + 2 * (jbase + (jj_)); if (hp_ > 515) hp_ = 515;     \
        const u16* src_ = xT + ((size_t)b * XT_H + hp_) * XT_ROW + w0 * CIN;  \
        u16* dst_ = &s[((jj_) % NSL) * SLOT_E];                               \
        gl2lds(src_ + wave * 512 + (lane << 3), dst_ + wave * 512);           \
        if (wave < 2)                                                         \
            gl2lds(src_ + (wave + 8) * 512 + (lane << 3), dst_ + (wave + 8) * 512); \
    } while (0)

    // stage weights for r-row r_ into wbuf: 36 x 1KB chunks.
    #define STAGE_W(r_) do {                                                  \
        const u16* src_ = wrep + (size_t)(r_) * WBUF_E;                       \
        _Pragma("unroll")                                                     \
        for (int k_ = 0; k_ < 5; ++k_) {                                      \
            int c_ = wave + 8 * k_;                                           \
            if (c_ < 36)                                                      \
                gl2lds(src_ + c_ * 512 + (lane << 3), wb + c_ * 512);         \
        }                                                                     \
    } while (0)

    // ---- prologue: rows 0..7 + weights r=0 ----
    #pragma unroll 1
    for (int jj = 0; jj < 8; ++jj) STAGE_X_ROW(jj);
    STAGE_W(0);
    __syncthreads();   // drains DMA (vmcnt(0)+barrier)

    const int  abase = RING_E + li * CIN + 8 * h;
    const int  bbase = (64 * wp + li) * CIN + 8 * h;

    floatx4 acc[4][4];

    #pragma unroll 1
    for (int st = 0; st < STEPS2; ++st) {
        #pragma unroll
        for (int mi = 0; mi < 4; ++mi)
            #pragma unroll
            for (int ni = 0; ni < 4; ++ni)
                acc[mi][ni] = (floatx4){0.f, 0.f, 0.f, 0.f};

        #pragma unroll 1
        for (int r = 0; r < KH; ++r) {
            // ---- taps(r): 9 kw x (4 A + 4 B ds_read_b128 + 16 MFMA) ----
            const int jj = 4 * st + wo + r;
            const u16* bb = &s[(jj % NSL) * SLOT_E] + bbase - 0;
            const u16* ab = &s[0] + abase;
            #pragma unroll
            for (int kw = 0; kw < KW; ++kw) {
                short8 af[4], bf_[4];
                #pragma unroll
                for (int mi = 0; mi < 4; ++mi)
                    af[mi] = *(const short8*)(ab + (kw * COUT + mi * 16) * CIN);
                #pragma unroll
                for (int ni = 0; ni < 4; ++ni)
                    bf_[ni] = *(const short8*)(bb + (16 * ni + 3 * kw) * CIN);
                __builtin_amdgcn_s_setprio(1);
                #pragma unroll
                for (int mi = 0; mi < 4; ++mi)
                    #pragma unroll
                    for (int ni = 0; ni < 4; ++ni)
                        acc[mi][ni] = __builtin_amdgcn_mfma_f32_16x16x32_bf16(
                            af[mi], bf_[ni], acc[mi][ni], 0, 0, 0);
                __builtin_amdgcn_s_setprio(0);
            }

            // ---- sync; issue next DMAs; sync (drain) ----
            __syncthreads();                       // all waves done with wbuf(r)
            if (r < KH - 1) {
                STAGE_W(r + 1);
            } else if (st < STEPS2 - 1) {
                STAGE_W(0);                        // next step's r=0
            }
            if (r == 0 && st < STEPS2 - 1) {       // prefetch next step's 4 rows
                #pragma unroll
                for (int rr = 0; rr < 4; ++rr) STAGE_X_ROW(4 * st + 8 + rr);
            }
            __syncthreads();                       // vmcnt(0) drain + barrier
        }

        // ---- store this step's row ----
        const int oh = parity + 2 * (jbase + 4 * st + wo);
        if (oh < OH) {
            #pragma unroll
            for (int ni = 0; ni < 4; ++ni) {
                const int posb = w0 + 64 * wp + 16 * ni;
                if (posb < OW) {
                    const int pos = posb + li;
                    #pragma unroll
                    for (int mi = 0; mi < 4; ++mi) {
                        float* op = out + (((size_t)(b * COUT + 16 * mi + 4 * h) * OH + oh) * OW) + pos;
                        #pragma unroll
                        for (int reg = 0; reg < 4; ++reg)
                            op[(size_t)reg * OH * OW] = acc[mi][ni][reg];
                    }
                }
            }
        }
    }
    #undef STAGE_X_ROW
    #undef STAGE_W
}

// ---------------- Fallback: round-9 parity-ring kernel ----------------
#define WTILE 128
#define SW 152
#define OCT_STRIDE 1224
#define SLOT_STRIDE 4896
#define NSLOT 8
#define NIT 304
#define STEPS 16

__global__ __launch_bounds__(256, 2)
void conv_ring(const float* __restrict__ x, const u16* __restrict__ wrep,
               float* __restrict__ out) {
    __shared__ u16 s[NSLOT * SLOT_STRIDE];

    const int bx     = blockIdx.x;
    const int wt     = bx & 3;
    const int parity = bx >> 2;
    const int chunk  = blockIdx.y;
    const int b      = blockIdx.z;
    const int w0     = wt * WTILE;
    const int oh0    = parity + 64 * chunk;
    const int ihbase = oh0 - 2;
    const int iwbase = w0 - 4;

    const int tid  = threadIdx.x;
    const int lane = tid & 63;
    const int wave = tid >> 6;
    const int wp   = wave & 1;
    const int wo   = wave >> 1;
    const int li   = lane & 15;
    const int h    = lane >> 4;

    const size_t cstr = (size_t)HH * WW;
    const float* xb = x + (size_t)b * CIN * cstr;

    for (int it = tid; it < 6 * NIT; it += 256) {
        int j   = it / NIT;
        int rem = it - j * NIT;
        int w4  = rem >> 3;
        int q   = rem & 7;
        int ih  = ihbase + 2 * j;
        int iw0 = iwbase + 4 * w4;
        float4 m0 = {0,0,0,0}, m1 = {0,0,0,0}, m2 = {0,0,0,0}, m3 = {0,0,0,0};
        if ((unsigned)ih < HH && (unsigned)iw0 < WW) {
            const float* pp = xb + (size_t)(4 * q) * cstr + (size_t)ih * WW + iw0;
            m0 = *(const float4*)(pp);
            m1 = *(const float4*)(pp + cstr);
            m2 = *(const float4*)(pp + 2 * cstr);
            m3 = *(const float4*)(pp + 3 * cstr);
        }
        u16* dst = s + (j & 7) * SLOT_STRIDE + (q >> 1) * OCT_STRIDE + (q & 1) * 4;
        const float* f0 = (const float*)&m0; const float* f1 = (const float*)&m1;
        const float* f2 = (const float*)&m2; const float* f3 = (const float*)&m3;
        #pragma unroll
        for (int jj = 0; jj < 4; ++jj) {
            u32 lo = (u32)f2bf(f0[jj]) | ((u32)f2bf(f1[jj]) << 16);
            u32 hi = (u32)f2bf(f2[jj]) | ((u32)f2bf(f3[jj]) << 16);
            *(uint2*)(dst + (4 * w4 + jj) * 8) = make_uint2(lo, hi);
        }
    }
    __syncthreads();

    const u16* abase0 = wrep + li * CIN + 8 * h;
    const int  bfixed = h * OCT_STRIDE + (64 * wp + li) * 8;

    floatx4 acc[4][4];

    #pragma unroll 1
    for (int st = 0; st < STEPS; ++st) {
        #pragma unroll
        for (int mi = 0; mi < 4; ++mi)
            #pragma unroll
            for (int ni = 0; ni < 4; ++ni)
                acc[mi][ni] = (floatx4){0.f, 0.f, 0.f, 0.f};

        const bool doPref = (st < STEPS - 1);
        float4 pv[3][4];
        #pragma unroll
        for (int k = 0; k < 3; ++k) {
            #pragma unroll
            for (int c = 0; c < 4; ++c) pv[k][c] = (float4){0,0,0,0};
            int it = tid + 256 * k;
            if (doPref && it < 2 * NIT) {
                int second = (it >= NIT);
                int rem = it - (second ? NIT : 0);
                int j   = 2 * st + 6 + second;
                int w4  = rem >> 3;
                int q   = rem & 7;
                int ih  = ihbase + 2 * j;
                int iw0 = iwbase + 4 * w4;
                if ((unsigned)ih < HH && (unsigned)iw0 < WW) {
                    const float* pp = xb + (size_t)(4 * q) * cstr + (size_t)ih * WW + iw0;
                    pv[k][0] = *(const float4*)(pp);
                    pv[k][1] = *(const float4*)(pp + cstr);
                    pv[k][2] = *(const float4*)(pp + 2 * cstr);
                    pv[k][3] = *(const float4*)(pp + 3 * cstr);
                }
            }
        }

        const int js = 2 * st;
        #pragma unroll 1
        for (int r = 0; r < KH; ++r) {
            const u16* bb = s + ((js + wo + r) & 7) * SLOT_STRIDE + bfixed;
            const u16* ab = abase0 + (size_t)(r * KW) * (COUT * CIN);
            #pragma unroll
            for (int kw = 0; kw < KW; ++kw) {
                short8 af[4], bf_[4];
                #pragma unroll
                for (int mi = 0; mi < 4; ++mi)
                    af[mi] = *(const short8*)(ab + (kw * COUT + mi * 16) * CIN);
                #pragma unroll
                for (int ni = 0; ni < 4; ++ni)
                    bf_[ni] = *(const short8*)(bb + (16 * ni + 3 * kw) * 8);
                __builtin_amdgcn_s_setprio(1);
                #pragma unroll
                for (int mi = 0; mi < 4; ++mi)
                    #pragma unroll
                    for (int ni = 0; ni < 4; ++ni)
                        acc[mi][ni] = __builtin_amdgcn_mfma_f32_16x16x32_bf16(
                            af[mi], bf_[ni], acc[mi][ni], 0, 0, 0);
                __builtin_amdgcn_s_setprio(0);
            }
        }

        if (doPref) {
            #pragma unroll
            for (int k = 0; k < 3; ++k) {
                int it = tid + 256 * k;
                if (it < 2 * NIT) {
                    int second = (it >= NIT);
                    int rem = it - (second ? NIT : 0);
                    int j   = 2 * st + 6 + second;
                    int w4  = rem >> 3;
                    int q   = rem & 7;
                    u16* dst = s + (j & 7) * SLOT_STRIDE + (q >> 1) * OCT_STRIDE + (q & 1) * 4;
                    const float* f0 = (const float*)&pv[k][0];
                    const float* f1 = (const float*)&pv[k][1];
                    const float* f2 = (const float*)&pv[k][2];
                    const float* f3 = (const float*)&pv[k][3];
                    #pragma unroll
                    for (int jj = 0; jj < 4; ++jj) {
                        u32 lo = (u32)f2bf(f0[jj]) | ((u32)f2bf(f1[jj]) << 16);
                        u32 hi = (u32)f2bf(f2[jj]) | ((u32)f2bf(f3[jj]) << 16);
                        *(uint2*)(dst + (4 * w4 + jj) * 8) = make_uint2(lo, hi);
                    }
                }
            }
        }
        __syncthreads();

        const int oh = oh0 + 4 * st + 2 * wo;
        if (oh < OH) {
            #pragma unroll
            for (int ni = 0; ni < 4; ++ni) {
                const int posb = w0 + 64 * wp + 16 * ni;
                if (posb < OW) {
                    const int pos = posb + li;
                    #pragma unroll
                    for (int mi = 0; mi < 4; ++mi) {
                        float* op = out + (((size_t)(b * COUT + 16 * mi + 4 * h) * OH + oh) * OW) + pos;
                        #pragma unroll
                        for (int reg = 0; reg < 4; ++reg)
                            op[(size_t)reg * OH * OW] = acc[mi][ni][reg];
                    }
                }
            }
        }
    }
}

extern "C" void kernel_launch(void* const* d_in, const int* in_sizes, int n_in,
                              void* d_out, int out_size, void* d_ws, size_t ws_size,
                              hipStream_t stream) {
    const float* x = (const float*)d_in[0];
    const float* w = (const float*)d_in[1];
    float* out = (float*)d_out;

    if (ws_size >= XT_BYTES + WREP_BYTES) {
        u16* xT   = (u16*)d_ws;
        u16* wrep = (u16*)((char*)d_ws + XT_BYTES);
        repack_w_k<<<(KH * KW * COUT * CIN + 255) / 256, 256, 0, stream>>>(w, wrep);
        dim3 tg((XT_W + 255) / 256, XT_H, 8);
        transpose_x<<<tg, 256, 0, stream>>>(x, xT);
        dim3 cg(8 /* wt(4) x parity(2) */, 4 /* chunks */, 8 /* batch */);
        conv_lds<<<cg, dim3(512), 0, stream>>>(xT, wrep, out);
    } else {
        u16* wrep = (u16*)d_ws;
        repack_w_k<<<(KH * KW * COUT * CIN + 255) / 256, 256, 0, stream>>>(w, wrep);
        dim3 grid(8, 8, 8);
        conv_ring<<<grid, dim3(256), 0, stream>>>(x, wrep, out);
    }
}

// Round 13
// 423.059 us; speedup vs baseline: 1.9979x; 1.1492x over previous
//
#include <hip/hip_runtime.h>

// Dilated conv2d, round 13: all-LDS implicit GEMM, wide wave tile.
// r12 budget: LDS-read port (555k cyc/CU) > MFMA (446k) -> LDS bytes bind.
// Change 1: wave tile 64co x 128pos (mi=4, ni=8, acc=128 AGPR): per-tap
//   12KB reads / 32 MFMA (was 8KB/16) = -25% LDS bytes; one wave per x-row.
//   8 waves = 8 rows/step; ring 12 slots + wbuf = 159.7KB; x-rows staged
//   staggered (row 8st+12+r after phase r; 4 rows after phase 4).
// Change 2: transpose vectorized (float2 pairs).

#define CIN 32
#define HH 512
#define WW 512
#define COUT 64
#define OH 508
#define OW 496
#define KH 5
#define KW 9

#define XT_H 516
#define XT_W 544
#define XT_ROW (XT_W * CIN)                    // 17408 elts
#define XT_ELTS ((size_t)8 * XT_H * XT_ROW)    // 71,860,224
#define XT_BYTES (XT_ELTS * 2)                 // 143,720,448
#define WREP_BYTES (KH * KW * COUT * CIN * 2)  // 184,320

#define WT2 128                  // pos tile
#define SLOT_W 160               // slot width (reads use <=152)
#define SLOT_E (SLOT_W * CIN)    // 5120 elts = 10,240B
#define NSL 12                   // ring slots
#define RING_E (NSL * SLOT_E)    // 61,440 elts
#define WBUF_E (KW * COUT * CIN) // 18,432 elts = 36,864B
#define STEPS2 8                 // 8 rows/step -> 64 parity-rows per block

typedef short short8 __attribute__((ext_vector_type(8)));
typedef float floatx4 __attribute__((ext_vector_type(4)));
typedef unsigned short u16;
typedef unsigned int u32;

__device__ __forceinline__ u16 f2bf(float f) {  // RNE f32->bf16
    u32 u = __float_as_uint(f);
    return (u16)((u + 0x7fffu + ((u >> 16) & 1u)) >> 16);
}

__device__ __forceinline__ void gl2lds(const u16* g, u16* l) {
    __builtin_amdgcn_global_load_lds(
        (const __attribute__((address_space(1))) unsigned int*)g,
        (__attribute__((address_space(3))) unsigned int*)l, 16, 0, 0);
}

__global__ void repack_w_k(const float* __restrict__ w, u16* __restrict__ wr) {
    int idx = blockIdx.x * 256 + threadIdx.x;
    if (idx >= KH * KW * COUT * CIN) return;
    int tap = idx / (COUT * CIN);
    int rem = idx - tap * (COUT * CIN);
    int co = rem / CIN;
    int ci = rem - co * CIN;
    int r  = tap / KW;
    int kw = tap - r * KW;
    wr[idx] = f2bf(w[((co * CIN + ci) * KH + r) * KW + kw]);
}

// K1: x [b][cin][h][w] f32 -> xT [b][h'=ih+2][w'=iw+4][cin] bf16, zero-padded.
// One thread per (w'-pair, h'): float2 loads per channel, 128B writes.
__global__ __launch_bounds__(128)
void transpose_x(const float* __restrict__ x, u16* __restrict__ xT) {
    int pr = blockIdx.x * 128 + threadIdx.x;   // pair index 0..271
    if (pr >= XT_W / 2) return;
    int wq = 2 * pr;
    int hp = blockIdx.y;
    int b  = blockIdx.z;
    int ih = hp - 2, iw0 = wq - 4;
    bool okh = (unsigned)ih < HH;
    bool ok0 = okh && ((unsigned)iw0 < WW);
    bool ok1 = okh && ((unsigned)(iw0 + 1) < WW);
    const float* xp = x + (size_t)b * CIN * (HH * WW) + (size_t)ih * WW + iw0;
    u16 v0[32], v1[32];
    if (ok0 && ok1) {
        #pragma unroll
        for (int c = 0; c < 32; ++c) {
            float2 f = *(const float2*)(xp + (size_t)c * (HH * WW));
            v0[c] = f2bf(f.x);
            v1[c] = f2bf(f.y);
        }
    } else {
        #pragma unroll
        for (int c = 0; c < 32; ++c) {
            v0[c] = ok0 ? f2bf(xp[(size_t)c * (HH * WW)]) : (u16)0;
            v1[c] = ok1 ? f2bf(xp[(size_t)c * (HH * WW) + 1]) : (u16)0;
        }
    }
    u16* dst = xT + (((size_t)b * XT_H + hp) * XT_W + wq) * CIN;
    #pragma unroll
    for (int k = 0; k < 4; ++k)
        *(uint4*)(dst + 8 * k) = *(const uint4*)&v0[8 * k];
    #pragma unroll
    for (int k = 0; k < 4; ++k)
        *(uint4*)(dst + CIN + 8 * k) = *(const uint4*)&v1[8 * k];
}

// K2: the conv. 512 thr / 8 waves, 1 block/CU, wave = 64co x 128pos x 1 row.
__global__ __launch_bounds__(512, 1)
void conv_lds(const u16* __restrict__ xT, const u16* __restrict__ wrep,
              float* __restrict__ out) {
    __shared__ u16 s[RING_E + WBUF_E];         // 159,744 B

    const int wt     = blockIdx.x & 3;
    const int parity = blockIdx.x >> 2;
    const int chunk  = blockIdx.y;             // 0..3
    const int b      = blockIdx.z;
    const int w0     = wt * WT2;
    const int jbase  = 64 * chunk;

    const int tid  = threadIdx.x;
    const int lane = tid & 63;
    const int wave = tid >> 6;                 // 0..7 = row within step (wo)
    const int li   = lane & 15;
    const int h    = lane >> 4;

    u16* wb = &s[RING_E];

    // stage local parity-row l_ into slot l_%12 (10 x 1KB chunks, 8 waves)
    #define STAGE_X_ROW(l_) do {                                              \
        int hp_ = parity + 2 * (jbase + (l_)); if (hp_ > 515) hp_ = 515;      \
        const u16* src_ = xT + ((size_t)b * XT_H + hp_) * XT_ROW + w0 * CIN;  \
        u16* dst_ = &s[((l_) % NSL) * SLOT_E];                                \
        gl2lds(src_ + wave * 512 + (lane << 3), dst_ + wave * 512);           \
        if (wave < 2)                                                         \
            gl2lds(src_ + (wave + 8) * 512 + (lane << 3), dst_ + (wave + 8) * 512); \
    } while (0)

    // stage weights for r-row r_ into wbuf (36 x 1KB chunks)
    #define STAGE_W(r_) do {                                                  \
        const u16* src_ = wrep + (size_t)(r_) * WBUF_E;                       \
        _Pragma("unroll")                                                     \
        for (int k_ = 0; k_ < 5; ++k_) {                                      \
            int c_ = wave + 8 * k_;                                           \
            if (c_ < 36)                                                      \
                gl2lds(src_ + c_ * 512 + (lane << 3), wb + c_ * 512);         \
        }                                                                     \
    } while (0)

    // ---- prologue: rows 0..11 + weights r=0 ----
    #pragma unroll 1
    for (int l = 0; l < 12; ++l) STAGE_X_ROW(l);
    STAGE_W(0);
    __syncthreads();

    const int abase = RING_E + li * CIN + 8 * h;
    const int bbase = li * CIN + 8 * h;

    floatx4 acc[4][8];

    #pragma unroll 1
    for (int st = 0; st < STEPS2; ++st) {
        #pragma unroll
        for (int mi = 0; mi < 4; ++mi)
            #pragma unroll
            for (int ni = 0; ni < 8; ++ni)
                acc[mi][ni] = (floatx4){0.f, 0.f, 0.f, 0.f};

        #pragma unroll 1
        for (int r = 0; r < KH; ++r) {
            const int jj = 8 * st + wave + r;
            const u16* bb = &s[(jj % NSL) * SLOT_E] + bbase;
            const u16* ab = &s[0] + abase;
            #pragma unroll
            for (int kw = 0; kw < KW; ++kw) {
                short8 af[4], bf_[8];
                #pragma unroll
                for (int mi = 0; mi < 4; ++mi)
                    af[mi] = *(const short8*)(ab + (kw * COUT + mi * 16) * CIN);
                #pragma unroll
                for (int ni = 0; ni < 8; ++ni)
                    bf_[ni] = *(const short8*)(bb + (16 * ni + 3 * kw) * CIN);
                __builtin_amdgcn_s_setprio(1);
                #pragma unroll
                for (int mi = 0; mi < 4; ++mi)
                    #pragma unroll
                    for (int ni = 0; ni < 8; ++ni)
                        acc[mi][ni] = __builtin_amdgcn_mfma_f32_16x16x32_bf16(
                            af[mi], bf_[ni], acc[mi][ni], 0, 0, 0);
                __builtin_amdgcn_s_setprio(0);
            }

            __syncthreads();                   // all waves done with wbuf(r) / freed row
            if (st < STEPS2 - 1) {
                if (r < 4) {
                    STAGE_X_ROW(8 * st + 12 + r);      // row 8st+r just died
                } else {
                    STAGE_X_ROW(8 * st + 16);          // rows 8st+4..7 just died
                    STAGE_X_ROW(8 * st + 17);
                    STAGE_X_ROW(8 * st + 18);
                    STAGE_X_ROW(8 * st + 19);
                }
            }
            if (r < 4) STAGE_W(r + 1);
            else if (st < STEPS2 - 1) STAGE_W(0);
            __syncthreads();                   // vmcnt(0) drain + barrier
        }

        // ---- store this step's row (wave owns full 128-pos tile) ----
        const int oh = parity + 2 * (jbase + 8 * st + wave);
        if (oh < OH) {
            #pragma unroll
            for (int ni = 0; ni < 8; ++ni) {
                const int posb = w0 + 16 * ni;
                if (posb < OW) {
                    const int pos = posb + li;
                    #pragma unroll
                    for (int mi = 0; mi < 4; ++mi) {
                        float* op = out + (((size_t)(b * COUT + 16 * mi + 4 * h) * OH + oh) * OW) + pos;
                        #pragma unroll
                        for (int reg = 0; reg < 4; ++reg)
                            op[(size_t)reg * OH * OW] = acc[mi][ni][reg];
                    }
                }
            }
        }
    }
    #undef STAGE_X_ROW
    #undef STAGE_W
}

// ---------------- Fallback: round-9 parity-ring kernel ----------------
#define WTILE 128
#define SW 152
#define OCT_STRIDE 1224
#define SLOT_STRIDE 4896
#define NSLOT 8
#define NIT 304
#define STEPS 16

__global__ __launch_bounds__(256, 2)
void conv_ring(const float* __restrict__ x, const u16* __restrict__ wrep,
               float* __restrict__ out) {
    __shared__ u16 s[NSLOT * SLOT_STRIDE];

    const int bx     = blockIdx.x;
    const int wt     = bx & 3;
    const int parity = bx >> 2;
    const int chunk  = blockIdx.y;
    const int b      = blockIdx.z;
    const int w0     = wt * WTILE;
    const int oh0    = parity + 64 * chunk;
    const int ihbase = oh0 - 2;
    const int iwbase = w0 - 4;

    const int tid  = threadIdx.x;
    const int lane = tid & 63;
    const int wave = tid >> 6;
    const int wp   = wave & 1;
    const int wo   = wave >> 1;
    const int li   = lane & 15;
    const int h    = lane >> 4;

    const size_t cstr = (size_t)HH * WW;
    const float* xb = x + (size_t)b * CIN * cstr;

    for (int it = tid; it < 6 * NIT; it += 256) {
        int j   = it / NIT;
        int rem = it - j * NIT;
        int w4  = rem >> 3;
        int q   = rem & 7;
        int ih  = ihbase + 2 * j;
        int iw0 = iwbase + 4 * w4;
        float4 m0 = {0,0,0,0}, m1 = {0,0,0,0}, m2 = {0,0,0,0}, m3 = {0,0,0,0};
        if ((unsigned)ih < HH && (unsigned)iw0 < WW) {
            const float* pp = xb + (size_t)(4 * q) * cstr + (size_t)ih * WW + iw0;
            m0 = *(const float4*)(pp);
            m1 = *(const float4*)(pp + cstr);
            m2 = *(const float4*)(pp + 2 * cstr);
            m3 = *(const float4*)(pp + 3 * cstr);
        }
        u16* dst = s + (j & 7) * SLOT_STRIDE + (q >> 1) * OCT_STRIDE + (q & 1) * 4;
        const float* f0 = (const float*)&m0; const float* f1 = (const float*)&m1;
        const float* f2 = (const float*)&m2; const float* f3 = (const float*)&m3;
        #pragma unroll
        for (int jj = 0; jj < 4; ++jj) {
            u32 lo = (u32)f2bf(f0[jj]) | ((u32)f2bf(f1[jj]) << 16);
            u32 hi = (u32)f2bf(f2[jj]) | ((u32)f2bf(f3[jj]) << 16);
            *(uint2*)(dst + (4 * w4 + jj) * 8) = make_uint2(lo, hi);
        }
    }
    __syncthreads();

    const u16* abase0 = wrep + li * CIN + 8 * h;
    const int  bfixed = h * OCT_STRIDE + (64 * wp + li) * 8;

    floatx4 acc[4][4];

    #pragma unroll 1
    for (int st = 0; st < STEPS; ++st) {
        #pragma unroll
        for (int mi = 0; mi < 4; ++mi)
            #pragma unroll
            for (int ni = 0; ni < 4; ++ni)
                acc[mi][ni] = (floatx4){0.f, 0.f, 0.f, 0.f};

        const bool doPref = (st < STEPS - 1);
        float4 pv[3][4];
        #pragma unroll
        for (int k = 0; k < 3; ++k) {
            #pragma unroll
            for (int c = 0; c < 4; ++c) pv[k][c] = (float4){0,0,0,0};
            int it = tid + 256 * k;
            if (doPref && it < 2 * NIT) {
                int second = (it >= NIT);
                int rem = it - (second ? NIT : 0);
                int j   = 2 * st + 6 + second;
                int w4  = rem >> 3;
                int q   = rem & 7;
                int ih  = ihbase + 2 * j;
                int iw0 = iwbase + 4 * w4;
                if ((unsigned)ih < HH && (unsigned)iw0 < WW) {
                    const float* pp = xb + (size_t)(4 * q) * cstr + (size_t)ih * WW + iw0;
                    pv[k][0] = *(const float4*)(pp);
                    pv[k][1] = *(const float4*)(pp + cstr);
                    pv[k][2] = *(const float4*)(pp + 2 * cstr);
                    pv[k][3] = *(const float4*)(pp + 3 * cstr);
                }
            }
        }

        const int js = 2 * st;
        #pragma unroll 1
        for (int r = 0; r < KH; ++r) {
            const u16* bb = s + ((js + wo + r) & 7) * SLOT_STRIDE + bfixed;
            const u16* ab = abase0 + (size_t)(r * KW) * (COUT * CIN);
            #pragma unroll
            for (int kw = 0; kw < KW; ++kw) {
                short8 af[4], bf_[4];
                #pragma unroll
                for (int mi = 0; mi < 4; ++mi)
                    af[mi] = *(const short8*)(ab + (kw * COUT + mi * 16) * CIN);
                #pragma unroll
                for (int ni = 0; ni < 4; ++ni)
                    bf_[ni] = *(const short8*)(bb + (16 * ni + 3 * kw) * 8);
                __builtin_amdgcn_s_setprio(1);
                #pragma unroll
                for (int mi = 0; mi < 4; ++mi)
                    #pragma unroll
                    for (int ni = 0; ni < 4; ++ni)
                        acc[mi][ni] = __builtin_amdgcn_mfma_f32_16x16x32_bf16(
                            af[mi], bf_[ni], acc[mi][ni], 0, 0, 0);
                __builtin_amdgcn_s_setprio(0);
            }
        }

        if (doPref) {
            #pragma unroll
            for (int k = 0; k < 3; ++k) {
                int it = tid + 256 * k;
                if (it < 2 * NIT) {
                    int second = (it >= NIT);
                    int rem = it - (second ? NIT : 0);
                    int j   = 2 * st + 6 + second;
                    int w4  = rem >> 3;
                    int q   = rem & 7;
                    u16* dst = s + (j & 7) * SLOT_STRIDE + (q >> 1) * OCT_STRIDE + (q & 1) * 4;
                    const float* f0 = (const float*)&pv[k][0];
                    const float* f1 = (const float*)&pv[k][1];
                    const float* f2 = (const float*)&pv[k][2];
                    const float* f3 = (const float*)&pv[k][3];
                    #pragma unroll
                    for (int jj = 0; jj < 4; ++jj) {
                        u32 lo = (u32)f2bf(f0[jj]) | ((u32)f2bf(f1[jj]) << 16);
                        u32 hi = (u32)f2bf(f2[jj]) | ((u32)f2bf(f3[jj]) << 16);
                        *(uint2*)(dst + (4 * w4 + jj) * 8) = make_uint2(lo, hi);
                    }
                }
            }
        }
        __syncthreads();

        const int oh = oh0 + 4 * st + 2 * wo;
        if (oh < OH) {
            #pragma unroll
            for (int ni = 0; ni < 4; ++ni) {
                const int posb = w0 + 64 * wp + 16 * ni;
                if (posb < OW) {
                    const int pos = posb + li;
                    #pragma unroll
                    for (int mi = 0; mi < 4; ++mi) {
                        float* op = out + (((size_t)(b * COUT + 16 * mi + 4 * h) * OH + oh) * OW) + pos;
                        #pragma unroll
                        for (int reg = 0; reg < 4; ++reg)
                            op[(size_t)reg * OH * OW] = acc[mi][ni][reg];
                    }
                }
            }
        }
    }
}

extern "C" void kernel_launch(void* const* d_in, const int* in_sizes, int n_in,
                              void* d_out, int out_size, void* d_ws, size_t ws_size,
                              hipStream_t stream) {
    const float* x = (const float*)d_in[0];
    const float* w = (const float*)d_in[1];
    float* out = (float*)d_out;

    if (ws_size >= XT_BYTES + WREP_BYTES) {
        u16* xT   = (u16*)d_ws;
        u16* wrep = (u16*)((char*)d_ws + XT_BYTES);
        repack_w_k<<<(KH * KW * COUT * CIN + 255) / 256, 256, 0, stream>>>(w, wrep);
        dim3 tg((XT_W / 2 + 127) / 128, XT_H, 8);
        transpose_x<<<tg, 128, 0, stream>>>(x, xT);
        dim3 cg(8 /* wt(4) x parity(2) */, 4 /* chunks */, 8 /* batch */);
        conv_lds<<<cg, dim3(512), 0, stream>>>(xT, wrep, out);
    } else {
        u16* wrep = (u16*)d_ws;
        repack_w_k<<<(KH * KW * COUT * CIN + 255) / 256, 256, 0, stream>>>(w, wrep);
        dim3 grid(8, 8, 8);
        conv_ring<<<grid, dim3(256), 0, stream>>>(x, wrep, out);
    }
}